// Round 3
// baseline (96.028 us; speedup 1.0000x reference)
//
#include <hip/hip_runtime.h>
#include <hip/hip_bf16.h>
#include <cstdint>

#define BATCH   16384
#define INDIM   512
#define OUTDIM  128
#define NINT    31
#define BM      64
#define THREADS 1024

// ws layout (bytes)
#define WS_WBF    0u        // bf16 [64][512]  (rows 62,63 zero-pad)
#define WS_LEAFT  65536u    // bf16 [128 col][64 node] (node 63 zero)
#define WS_BIAS   81920u    // f32 [64] (62,63 zero)
#define WS_GSM0   82176u    // f32 [31]
#define WS_GSM1   82432u    // f32 [31]

typedef __attribute__((ext_vector_type(8))) short s8v;   // 8 bf16
typedef __attribute__((ext_vector_type(4))) float f4v;   // MFMA acc

__device__ __forceinline__ short bfs(float f) {
    return (short)__builtin_bit_cast(unsigned short, __float2bfloat16(f));
}
__device__ __forceinline__ unsigned int pk2(float lo, float hi) {
    return (unsigned int)(unsigned short)bfs(lo) |
           ((unsigned int)(unsigned short)bfs(hi) << 16);
}

// XOR swizzle on 8-elem (16B) granularity: spreads the 128B-row-stride bank
// pattern of cbf across 8 slots -> residual 2-way conflict is free (m136).
#define SWZ(r, k) ((k) ^ (((r) & 7) << 3))

// ---------------- prep: one-time constant conversion into ws ----------------
__global__ __launch_bounds__(256) void prep_kernel(
    const float* __restrict__ W, const float* __restrict__ bvec,
    const float* __restrict__ gamma, const float* __restrict__ leaf,
    unsigned char* __restrict__ ws)
{
    unsigned short* wbf = (unsigned short*)(ws + WS_WBF);
    unsigned short* lT  = (unsigned short*)(ws + WS_LEAFT);
    float* bias = (float*)(ws + WS_BIAS);
    float* g0v  = (float*)(ws + WS_GSM0);
    float* g1v  = (float*)(ws + WS_GSM1);
    const int tid  = blockIdx.x * 256 + threadIdx.x;
    const int nthr = gridDim.x * 256;

    for (int i = tid; i < 64 * INDIM; i += nthr) {           // W -> bf16, rows 62,63 = 0
        int r = i >> 9;
        float v = (r < 62) ? W[i] : 0.0f;                    // W is [31][2][512] == [62][512]
        wbf[i] = (unsigned short)bfs(v);
    }
    for (int i = tid; i < OUTDIM * 64; i += nthr) {          // leaf^T bf16 [col][node]
        int n = i & 63, col = i >> 6;
        float v = (n < 63) ? leaf[(size_t)n * OUTDIM + col] : 0.0f;
        lT[i] = (unsigned short)bfs(v);
    }
    if (tid < 64) bias[tid] = (tid < 62) ? bvec[tid] : 0.0f;
    if (tid < NINT) {
        float a = gamma[2*tid], b = gamma[2*tid+1];
        float m = fmaxf(a, b);
        float e0 = __expf(a - m), e1 = __expf(b - m);
        float inv = 1.0f / (e0 + e1);
        g0v[tid] = e0 * inv;
        g1v[tid] = e1 * inv;
    }
}

// ---------------- main: 16 waves/block, 4-way K-split logits GEMM ----------------
__global__ __launch_bounds__(THREADS) void mix_main(
    const float* __restrict__ x, const unsigned char* __restrict__ ws,
    float* __restrict__ out)
{
    __shared__ __align__(16) float Lgp[4][BM][65];          // partial logits per k-quarter
    __shared__ __align__(16) unsigned short cbf[BM][64];    // coefficients bf16, swizzled
    __shared__ float gsh0[NINT], gsh1[NINT];

    const int t    = threadIdx.x;
    const int lane = t & 63;
    const int w    = t >> 6;       // wave 0..15
    const int rg   = w & 3;        // row group: rows 16rg..16rg+15
    const int kg   = w >> 2;       // k quarter: k in [128kg, 128kg+128)
    const int g    = lane >> 4;    // 8-elem k-slot group
    const int lm   = lane & 15;
    const int row0 = blockIdx.x * BM;

    if (t < NINT) {
        gsh0[t] = ((const float*)(ws + WS_GSM0))[t];
        gsh1[t] = ((const float*)(ws + WS_GSM1))[t];
    }

    // bias folded into k-quarter 0's accumulator only
    const float* bias = (const float*)(ws + WS_BIAS);
    f4v acc[4];
    #pragma unroll
    for (int c = 0; c < 4; ++c) {
        float b = (kg == 0) ? bias[16*c + lm] : 0.0f;
        acc[c] = (f4v){b, b, b, b};
    }

    // ---- P1: partial logits, direct-global x, bf16 W from L2, no barriers ----
    const float* xrow = x + (size_t)(row0 + 16*rg + lm) * INDIM + 128*kg;
    const unsigned short* wb = (const unsigned short*)(ws + WS_WBF) + 128*kg;
    #pragma unroll
    for (int ks = 0; ks < 4; ++ks) {
        const int k0 = ks * 32 + 8 * g;
        float4 x0 = *(const float4*)(xrow + k0);
        float4 x1 = *(const float4*)(xrow + k0 + 4);
        s8v a;
        a[0] = bfs(x0.x); a[1] = bfs(x0.y); a[2] = bfs(x0.z); a[3] = bfs(x0.w);
        a[4] = bfs(x1.x); a[5] = bfs(x1.y); a[6] = bfs(x1.z); a[7] = bfs(x1.w);
        #pragma unroll
        for (int c = 0; c < 4; ++c) {
            s8v b = *(const s8v*)(wb + (size_t)(16*c + lm) * INDIM + k0);
            acc[c] = __builtin_amdgcn_mfma_f32_16x16x32_bf16(a, b, acc[c], 0, 0, 0);
        }
    }
    // C/D layout (HW-verified): col = lane&15, row = 4*(lane>>4) + reg
    #pragma unroll
    for (int c = 0; c < 4; ++c)
        #pragma unroll
        for (int r = 0; r < 4; ++r)
            Lgp[kg][16*rg + 4*g + r][16*c + lm] = acc[c][r];
    __syncthreads();

    // ---- combine the 4 k-quarters (1024 threads, 4 cols each) ----
    {
        const int row = t >> 4;
        const int c0  = (t & 15) * 4;
        #pragma unroll
        for (int j = 0; j < 4; ++j) {
            const int c = c0 + j;
            Lgp[0][row][c] += Lgp[1][row][c] + Lgp[2][row][c] + Lgp[3][row][c];
        }
    }
    __syncthreads();

    // ---- P2: per-row tree walk (64 lanes of wave 0), incremental bf16 packing ----
    if (t < BM) {
        const int row = t;
        float Pp[63];
        unsigned int cvp[32];
        float sv = 0.0f;
        Pp[0] = 1.0f;
        #pragma unroll
        for (int n = 0; n < NINT; ++n) {
            float l0 = Lgp[0][row][2*n];
            float l1 = Lgp[0][row][2*n + 1];
            float r1 = 1.0f / (1.0f + __expf(l0 - l1));      // softmax pair, overflow-safe
            float base = Pp[n] * gsh0[n];
            Pp[2*n + 1] = base * (1.0f - r1);
            Pp[2*n + 2] = base * r1;
            float cval = Pp[n] * gsh1[n];
            if (n & 1) cvp[n >> 1] = pk2(sv, cval); else sv = cval;
        }
        #pragma unroll
        for (int n = NINT; n < 63; ++n) {
            float cval = Pp[n];
            if (n & 1) cvp[n >> 1] = pk2(sv, cval); else sv = cval;
        }
        cvp[31] = pk2(sv, 0.0f);                             // cv[62], pad node 63 = 0
        #pragma unroll
        for (int j = 0; j < 8; ++j) {
            int p = SWZ(row, 8 * j);
            *(uint4*)&cbf[row][p] =
                make_uint4(cvp[4*j], cvp[4*j+1], cvp[4*j+2], cvp[4*j+3]);
        }
    }
    __syncthreads();

    // ---- P3: Out[64][128] = C @ leaf (K=64); wave w does rows rg, cols {2kg,2kg+1} ----
    const unsigned short* lT = (const unsigned short*)(ws + WS_LEAFT);
    f4v o[2] = {};
    #pragma unroll
    for (int kw = 0; kw < 2; ++kw) {
        const int k0 = kw * 32 + 8 * g;
        s8v a = *(const s8v*)&cbf[16*rg + lm][SWZ(lm, k0)];  // (16rg+lm)&7 == lm&7
        #pragma unroll
        for (int j = 0; j < 2; ++j) {
            s8v b = *(const s8v*)(lT + (size_t)(16*(2*kg + j) + lm) * 64 + k0);
            o[j] = __builtin_amdgcn_mfma_f32_16x16x32_bf16(a, b, o[j], 0, 0, 0);
        }
    }
    #pragma unroll
    for (int j = 0; j < 2; ++j)
        #pragma unroll
        for (int r = 0; r < 4; ++r)
            out[(size_t)(row0 + 16*rg + 4*g + r) * OUTDIM + 16*(2*kg + j) + lm] = o[j][r];
}

extern "C" void kernel_launch(void* const* d_in, const int* in_sizes, int n_in,
                              void* d_out, int out_size, void* d_ws, size_t ws_size,
                              hipStream_t stream) {
    const float* x     = (const float*)d_in[0];
    const float* W     = (const float*)d_in[1];
    const float* b     = (const float*)d_in[2];
    const float* gamma = (const float*)d_in[3];
    const float* leaf  = (const float*)d_in[4];
    float* out = (float*)d_out;
    hipLaunchKernelGGL(prep_kernel, dim3(128), dim3(256), 0, stream,
                       W, b, gamma, leaf, (unsigned char*)d_ws);
    hipLaunchKernelGGL(mix_main, dim3(BATCH / BM), dim3(THREADS), 0, stream,
                       x, (const unsigned char*)d_ws, out);
}